// Round 9
// baseline (112.782 us; speedup 1.0000x reference)
//
#include <hip/hip_runtime.h>
#include <hip/hip_bf16.h>
#include <cstdint>
#include <cstddef>

// Problem constants (fixed by the reference: anchor/positive [4096,512] f32, labels [4096] i32)
constexpr int BN = 4096;   // batch
constexpr int DN = 512;    // feature dim
constexpr int NT = BN / 128;              // 32 tiles per dim
constexpr int NBLK = NT * (NT + 1) / 2;   // 528 triangular tile-pairs
constexpr float MARGIN = 0.2f;
constexpr uint32_t INF_U = 0x7f800000u;   // +inf bits; positive-float order == uint order

typedef __attribute__((ext_vector_type(8))) short short8;     // 8 bf16 = 4 VGPRs (MFMA A/B frag)
typedef __attribute__((ext_vector_type(4))) float float4v;    // MFMA C/D frag

// ---------------------------------------------------------------------------
// Kernel 1: per-row stats + bf16 cast of anchor + init of min arrays + counter.
// One wave per row (4 rows / 256-thread block). Lane l owns elems [8l, 8l+8).
// meta[row] = {||a||^2, d_ap(squared), d_ap^2, label-bits}  (one b128 load later)
// ---------------------------------------------------------------------------
__global__ __launch_bounds__(256) void prep_kernel(
    const float* __restrict__ anchor,
    const float* __restrict__ positive,
    const int* __restrict__ labels,
    uint16_t* __restrict__ Abf,        // [BN][DN] bf16 bits
    float4* __restrict__ meta,         // [BN]
    uint32_t* __restrict__ min_all,    // [BN] +inf-initialized (min over d2)
    uint32_t* __restrict__ min_larger, // [BN] +inf-initialized (min over d2)
    uint32_t* __restrict__ done_count) // single counter, zeroed here
{
    const int tid  = threadIdx.x;
    const int wave = tid >> 6;
    const int lane = tid & 63;
    const int row  = blockIdx.x * 4 + wave;

    if (blockIdx.x == 0 && tid == 0) *done_count = 0;

    const float4* arow = (const float4*)(anchor   + (size_t)row * DN);
    const float4* prow = (const float4*)(positive + (size_t)row * DN);

    float4 av0 = arow[lane * 2 + 0], av1 = arow[lane * 2 + 1];
    float4 pv0 = prow[lane * 2 + 0], pv1 = prow[lane * 2 + 1];

    float a[8] = {av0.x, av0.y, av0.z, av0.w, av1.x, av1.y, av1.z, av1.w};
    float p[8] = {pv0.x, pv0.y, pv0.z, pv0.w, pv1.x, pv1.y, pv1.z, pv1.w};

    float s = 0.f, d = 0.f;
    union { uint16_t u[8]; uint4 v; } pk;
    #pragma unroll
    for (int i = 0; i < 8; ++i) {
        s += a[i] * a[i];
        float dx = a[i] - p[i];
        d += dx * dx;
        uint32_t ub = __float_as_uint(a[i]);               // RNE f32 -> bf16
        pk.u[i] = (uint16_t)((ub + 0x7fffu + ((ub >> 16) & 1u)) >> 16);
    }

    ((uint4*)(Abf + (size_t)row * DN))[lane] = pk.v;       // 16B coalesced store

    #pragma unroll
    for (int off = 32; off; off >>= 1) {
        s += __shfl_xor(s, off);
        d += __shfl_xor(d, off);
    }
    if (lane == 0) {
        meta[row] = (float4){s, d, d * d, __uint_as_float((uint32_t)labels[row])};
        min_all[row]    = INF_U;
        min_larger[row] = INF_U;
    }
}

// ---------------------------------------------------------------------------
// Kernel 2: upper-triangular 128x128 tiles of S = A·A^T (bf16 MFMA 16x16x32).
// WAVE-PRIVATE LDS TILES, ZERO K-LOOP BARRIERS: each wave stages its own
// A(64x32) + B(64x32) bf16 tiles in a private 8 KB LDS region. ds_write ->
// ds_read within one wave is ordered by the in-order per-wave LDS pipeline +
// lgkmcnt — no __syncthreads. 12 waves/CU (3 blocks x 4) become fully
// independent streams; barrier-coupled stalls (the invariant across R3/R4/
// R6/R8, all 42-58 µs) are gone. Cost: tile duplication -> 2x global traffic
// (~270 MB, L2-resident Abf) and 256 ds-ops/wave; LDS-port floor ~10.5 µs/CU.
// Staging: 8 named uint4 scalars (R8-proven spill-free; R2/R7 arrays spilled),
// register-prefetch of tile kt+1 issued right after kt's ds_writes.
// Swizzle: LDS row stride 64 B, slot = chunk ^ ((row>>1)&3). Derivation:
// write instr (rows l>>2 + 16i) and frag-read instr (row = mi*16+l15,
// chunk = quad) both place exactly 8 lanes on each 16B-phase -> conflict-free.
// TRIPWIRES: SQ_LDS_BANK_CONFLICT ~0, WRITE_SIZE ~5 MB, VGPR <= 170.
// Epilogue: squared-distance dual-side masked mins via uint atomicMin.
// Last block (device counter) folds in the finalize: select, sqrt, hinge, mean.
// ---------------------------------------------------------------------------
__global__ __launch_bounds__(256, 3) void gram_kernel(
    const uint16_t* __restrict__ Abf,
    const float4* __restrict__ meta,
    uint32_t* __restrict__ min_all,
    uint32_t* __restrict__ min_larger,
    uint32_t* __restrict__ done_count,
    float* __restrict__ out)
{
    __shared__ uint16_t lds[4 * 4096];   // 32 KB: 8 KB per wave (A 4 KB + B 4 KB)

    // triangular decode: blockIdx.x -> (bi, bj) with bi <= bj
    int t = blockIdx.x, bi = 0, rem = NT;
    while (t >= rem) { t -= rem; ++bi; --rem; }
    const int bj = bi + t;
    const bool offdiag = (bi != bj);
    const int rowBase = bi * 128;
    const int colBase = bj * 128;

    const int tid  = threadIdx.x;
    const int lane = tid & 63;
    const int wave = tid >> 6;
    const int wi   = wave >> 1;       // wave row in 2x2 grid
    const int wj   = wave & 1;        // wave col
    const int quad = lane >> 4;
    const int l15  = lane & 15;

    uint16_t* const Aw = lds + wave * 4096;   // this wave's A tile (2048 elems)
    uint16_t* const Bw = Aw + 2048;           // this wave's B tile

    // Staging map: lane covers rows (lane>>2)+16i, i=0..3, chunk lane&3 (16 B).
    // LDS slot = chunk ^ ((row>>1)&3); (row>>1)&3 == (lane>>3)&3 for all i.
    const int srow  = lane >> 2;
    const int sc    = lane & 3;
    const int sslot = sc ^ ((lane >> 3) & 3);

    const uint16_t* const gA = Abf + (size_t)(rowBase + wi * 64 + srow) * DN + sc * 8;
    const uint16_t* const gB = Abf + (size_t)(colBase + wj * 64 + srow) * DN + sc * 8;

    uint16_t* const wA = Aw + srow * 32 + sslot * 8;   // +i*512 elems per i
    uint16_t* const wB = Bw + srow * 32 + sslot * 8;

    // Frag-read bases: row = mi*16 + l15, chunk = quad,
    // slot = quad ^ ((row>>1)&3) == quad ^ ((l15>>1)&3) for all mi.
    const int rs = quad ^ ((l15 >> 1) & 3);
    const uint16_t* const rA = Aw + l15 * 32 + rs * 8;  // +mi*512 per mi
    const uint16_t* const rB = Bw + l15 * 32 + rs * 8;

    // Prologue: tile 0 into 8 named staging scalars (32 VGPRs, SSA).
    uint4 qa0 = *(const uint4*)(gA + 0 * 16 * DN);
    uint4 qa1 = *(const uint4*)(gA + 1 * 16 * DN);
    uint4 qa2 = *(const uint4*)(gA + 2 * 16 * DN);
    uint4 qa3 = *(const uint4*)(gA + 3 * 16 * DN);
    uint4 qb0 = *(const uint4*)(gB + 0 * 16 * DN);
    uint4 qb1 = *(const uint4*)(gB + 1 * 16 * DN);
    uint4 qb2 = *(const uint4*)(gB + 2 * 16 * DN);
    uint4 qb3 = *(const uint4*)(gB + 3 * 16 * DN);

    float4v acc[4][4];
    #pragma unroll
    for (int i = 0; i < 4; ++i)
        #pragma unroll
        for (int j = 0; j < 4; ++j)
            acc[i][j] = (float4v){0.f, 0.f, 0.f, 0.f};

    #pragma unroll
    for (int kt = 0; kt < DN / 32; ++kt) {
        // stage tile kt (waits vmcnt for own loads only — no barrier)
        *(uint4*)(wA + 0 * 512) = qa0;
        *(uint4*)(wA + 1 * 512) = qa1;
        *(uint4*)(wA + 2 * 512) = qa2;
        *(uint4*)(wA + 3 * 512) = qa3;
        *(uint4*)(wB + 0 * 512) = qb0;
        *(uint4*)(wB + 1 * 512) = qb1;
        *(uint4*)(wB + 2 * 512) = qb2;
        *(uint4*)(wB + 3 * 512) = qb3;
        if (kt < DN / 32 - 1) {       // issue next tile's loads; land during MFMA
            const int ko = (kt + 1) * 32;
            qa0 = *(const uint4*)(gA + 0 * 16 * DN + ko);
            qa1 = *(const uint4*)(gA + 1 * 16 * DN + ko);
            qa2 = *(const uint4*)(gA + 2 * 16 * DN + ko);
            qa3 = *(const uint4*)(gA + 3 * 16 * DN + ko);
            qb0 = *(const uint4*)(gB + 0 * 16 * DN + ko);
            qb1 = *(const uint4*)(gB + 1 * 16 * DN + ko);
            qb2 = *(const uint4*)(gB + 2 * 16 * DN + ko);
            qb3 = *(const uint4*)(gB + 3 * 16 * DN + ko);
        }
        // frags (in-order LDS pipe guarantees writes above are visible)
        short8 a0 = *(const short8*)(rA + 0 * 512);
        short8 a1 = *(const short8*)(rA + 1 * 512);
        short8 a2 = *(const short8*)(rA + 2 * 512);
        short8 a3 = *(const short8*)(rA + 3 * 512);
        short8 b0 = *(const short8*)(rB + 0 * 512);
        short8 b1 = *(const short8*)(rB + 1 * 512);
        short8 b2 = *(const short8*)(rB + 2 * 512);
        short8 b3 = *(const short8*)(rB + 3 * 512);

        acc[0][0] = __builtin_amdgcn_mfma_f32_16x16x32_bf16(a0, b0, acc[0][0], 0, 0, 0);
        acc[0][1] = __builtin_amdgcn_mfma_f32_16x16x32_bf16(a0, b1, acc[0][1], 0, 0, 0);
        acc[0][2] = __builtin_amdgcn_mfma_f32_16x16x32_bf16(a0, b2, acc[0][2], 0, 0, 0);
        acc[0][3] = __builtin_amdgcn_mfma_f32_16x16x32_bf16(a0, b3, acc[0][3], 0, 0, 0);
        acc[1][0] = __builtin_amdgcn_mfma_f32_16x16x32_bf16(a1, b0, acc[1][0], 0, 0, 0);
        acc[1][1] = __builtin_amdgcn_mfma_f32_16x16x32_bf16(a1, b1, acc[1][1], 0, 0, 0);
        acc[1][2] = __builtin_amdgcn_mfma_f32_16x16x32_bf16(a1, b2, acc[1][2], 0, 0, 0);
        acc[1][3] = __builtin_amdgcn_mfma_f32_16x16x32_bf16(a1, b3, acc[1][3], 0, 0, 0);
        acc[2][0] = __builtin_amdgcn_mfma_f32_16x16x32_bf16(a2, b0, acc[2][0], 0, 0, 0);
        acc[2][1] = __builtin_amdgcn_mfma_f32_16x16x32_bf16(a2, b1, acc[2][1], 0, 0, 0);
        acc[2][2] = __builtin_amdgcn_mfma_f32_16x16x32_bf16(a2, b2, acc[2][2], 0, 0, 0);
        acc[2][3] = __builtin_amdgcn_mfma_f32_16x16x32_bf16(a2, b3, acc[2][3], 0, 0, 0);
        acc[3][0] = __builtin_amdgcn_mfma_f32_16x16x32_bf16(a3, b0, acc[3][0], 0, 0, 0);
        acc[3][1] = __builtin_amdgcn_mfma_f32_16x16x32_bf16(a3, b1, acc[3][1], 0, 0, 0);
        acc[3][2] = __builtin_amdgcn_mfma_f32_16x16x32_bf16(a3, b2, acc[3][2], 0, 0, 0);
        acc[3][3] = __builtin_amdgcn_mfma_f32_16x16x32_bf16(a3, b3, acc[3][3], 0, 0, 0);
    }

    // ---- epilogue: squared distances, dual-side masked mins ----
    const float INFF = __uint_as_float(INF_U);
    float4 mj_meta[4];
    #pragma unroll
    for (int mj = 0; mj < 4; ++mj)
        mj_meta[mj] = meta[colBase + wj * 64 + mj * 16 + l15];   // C/D col = lane&15

    float cAll[4], cLarger[4];
    #pragma unroll
    for (int mj = 0; mj < 4; ++mj) { cAll[mj] = INFF; cLarger[mj] = INFF; }

    #pragma unroll
    for (int mi = 0; mi < 4; ++mi) {
        #pragma unroll
        for (int r = 0; r < 4; ++r) {
            int row = rowBase + wi * 64 + mi * 16 + quad * 4 + r;  // C/D row = quad*4+reg
            float4 mim = meta[row];          // {sqn, dap, dap^2, label}
            uint32_t li = __float_as_uint(mim.w);
            float mAll = INFF, mLarger = INFF;
            #pragma unroll
            for (int mj = 0; mj < 4; ++mj) {
                float d2 = mim.x + mj_meta[mj].x - 2.0f * acc[mi][mj][r];
                d2 = d2 > 0.f ? d2 : 0.f;
                if (__float_as_uint(mj_meta[mj].w) != li) {
                    mAll = fminf(mAll, d2);
                    // reference: pd (euclidean) > d_ap (squared)  <=>  d2 > dap^2
                    if (d2 > mim.z) mLarger = fminf(mLarger, d2);
                    if (offdiag) {
                        cAll[mj] = fminf(cAll[mj], d2);
                        if (d2 > mj_meta[mj].z) cLarger[mj] = fminf(cLarger[mj], d2);
                    }
                }
            }
            // min across the 16 lanes of this quad (they share `row`, cover 64 cols)
            #pragma unroll
            for (int off = 1; off < 16; off <<= 1) {
                mAll    = fminf(mAll,    __shfl_xor(mAll, off));
                mLarger = fminf(mLarger, __shfl_xor(mLarger, off));
            }
            if (l15 == 0) {
                atomicMin(&min_all[row],    __float_as_uint(mAll));
                atomicMin(&min_larger[row], __float_as_uint(mLarger));
            }
        }
    }
    if (offdiag) {
        // col j = colBase + wj*64 + mj*16 + l15 is shared by the 4 quads
        #pragma unroll
        for (int mj = 0; mj < 4; ++mj) {
            float a0 = cAll[mj], l0 = cLarger[mj];
            a0 = fminf(a0, __shfl_xor(a0, 16)); l0 = fminf(l0, __shfl_xor(l0, 16));
            a0 = fminf(a0, __shfl_xor(a0, 32)); l0 = fminf(l0, __shfl_xor(l0, 32));
            if (quad == 0) {
                int col = colBase + wj * 64 + mj * 16 + l15;
                atomicMin(&min_all[col],    __float_as_uint(a0));
                atomicMin(&min_larger[col], __float_as_uint(l0));
            }
        }
    }

    // ---- last-block finalize: select, sqrt, hinge, mean ----
    __shared__ bool isLast;
    __syncthreads();                      // all this block's atomics issued
    if (tid == 0) {
        __threadfence();                  // make our mins visible device-wide
        isLast = (atomicAdd(done_count, 1u) == NBLK - 1);
    }
    __syncthreads();
    if (isLast) {
        __threadfence();                  // acquire: see all other blocks' mins
        float s = 0.f;
        for (int i = tid; i < BN; i += 256) {
            uint32_t mlu = __hip_atomic_load(&min_larger[i], __ATOMIC_RELAXED, __HIP_MEMORY_SCOPE_AGENT);
            uint32_t mau = __hip_atomic_load(&min_all[i],    __ATOMIC_RELAXED, __HIP_MEMORY_SCOPE_AGENT);
            float dan2 = (mlu != INF_U) ? __uint_as_float(mlu) : __uint_as_float(mau);
            float l = meta[i].y - sqrtf(dan2) + MARGIN;
            s += l > 0.f ? l : 0.f;
        }
        #pragma unroll
        for (int off = 32; off; off >>= 1) s += __shfl_xor(s, off);
        __shared__ float wsum[4];
        if ((tid & 63) == 0) wsum[tid >> 6] = s;
        __syncthreads();
        if (tid == 0) out[0] = (wsum[0] + wsum[1] + wsum[2] + wsum[3]) * (1.0f / BN);
    }
}

// ---------------------------------------------------------------------------
extern "C" void kernel_launch(void* const* d_in, const int* in_sizes, int n_in,
                              void* d_out, int out_size, void* d_ws, size_t ws_size,
                              hipStream_t stream) {
    const float* anchor   = (const float*)d_in[0];
    const float* positive = (const float*)d_in[1];
    const int*   labels   = (const int*)d_in[2];
    float* out = (float*)d_out;

    // Workspace layout (~4.4 MB)
    uint8_t* ws = (uint8_t*)d_ws;
    uint16_t* Abf        = (uint16_t*)ws;                          // 4 MB bf16 anchor
    float4*   meta       = (float4*)(ws + (size_t)BN * DN * 2);    // 64 KB
    uint32_t* min_all    = (uint32_t*)(meta + BN);                 // 16 KB
    uint32_t* min_larger = min_all + BN;                           // 16 KB
    uint32_t* done_count = min_larger + BN;                        // 4 B

    prep_kernel<<<BN / 4, 256, 0, stream>>>(anchor, positive, labels, Abf, meta,
                                            min_all, min_larger, done_count);
    gram_kernel<<<NBLK, 256, 0, stream>>>(Abf, meta, min_all, min_larger, done_count, out);
}